// Round 5
// baseline (375.459 us; speedup 1.0000x reference)
//
#include <hip/hip_runtime.h>
#include <stdint.h>

// Bahdanau additive attention, MI355X / gfx950.
// Inputs fp32, outputs fp32 (ctx[32*512] ++ aw[32*2048]).
// B=32, T=2048, D=512, U=512.  M = B*T = 65536.
//
// R13: BARRIER-FREE attn_gemm. R2/R11/R12 all stall-bound (MfmaUtil 13-18%,
//      VALU 21-28%, rest = 16x per-k-step __syncthreads+vmcnt(0) drains).
//      New: A-fragments loaded DIRECTLY from feats (16 rows x 128B per wave,
//      100% line use, 2 dwordx4/lane + 4 cvt_pk in-reg), B from R11-verified
//      fragment-packed WkTf (L2-resident, 16B/lane). Zero LDS / zero barriers
//      in the k-loop; reg double-buffer (full unroll, static indices); TLP
//      (16 waves/CU) hides latency instead of lockstep barriers.
//      Wave = 32 rows x 64 cols; 8 waves = all N=512 -> lg written in-block.
//      Bank-conflict counter proven A-path-only (identical 2.6M w/ and w/o Bs).
// R12: 128x128 tiles + occupancy: regressed (105us). R11: B-from-L2 under
//      barriers: regressed (95us). R10: context atomics removed. R8: swizzles.

typedef unsigned short ushort_t;
typedef __attribute__((ext_vector_type(8))) short short8;
typedef __attribute__((ext_vector_type(4))) float f32x4;
typedef __attribute__((ext_vector_type(4))) uint32_t u32x4;
typedef __attribute__((ext_vector_type(2))) float float2v;
typedef __attribute__((ext_vector_type(2))) __bf16 bf162v;

__device__ __forceinline__ ushort_t f2bf(float f) {
    uint32_t u = __builtin_bit_cast(uint32_t, f);
    u = (u + 0x7fffu + ((u >> 16) & 1u)) >> 16;   // RNE
    return (ushort_t)u;
}
__device__ __forceinline__ uint32_t pkbf(float a, float b) {
    bf162v r = __builtin_convertvector((float2v){a, b}, bf162v);
    return __builtin_bit_cast(uint32_t, r);
}
__device__ __forceinline__ short8 cvt8(const f32x4 lo, const f32x4 hi) {
    u32x4 u = (u32x4){pkbf(lo.x, lo.y), pkbf(lo.z, lo.w),
                      pkbf(hi.x, hi.y), pkbf(hi.z, hi.w)};
    return __builtin_bit_cast(short8, u);
}

// --------------------------- fused prep: uh GEMV + WkTf fragment pack
// grid 512 = 256 uh | 256 WkTf
// WkTf[g=ks*32+n4][quad*128 + lc*8 + j] = bf16(Wk[ks*32+quad*8+j][n4*16+lc])
// (fragment layout harness-verified in R11)
__global__ __launch_bounds__(256) void prep_all(
    const float* __restrict__ hidden, const float* __restrict__ Uk,
    const float* __restrict__ Ub, const float* __restrict__ Wb,
    const float* __restrict__ Wk,
    float* __restrict__ uh, ushort_t* __restrict__ WkTf)
{
    const int pb = blockIdx.x;
    if (pb < 256) {
        const int b  = pb >> 3;
        const int u  = (pb & 7) * 64 + (threadIdx.x & 63);
        const int k0 = (threadIdx.x >> 6) * 128;
        const float* hr = hidden + b * 512;
        float acc = 0.f;
        #pragma unroll 8
        for (int k = k0; k < k0 + 128; ++k)
            acc += hr[k] * Uk[k * 512 + u];
        __shared__ float red[256];
        red[threadIdx.x] = acc;
        __syncthreads();
        if (threadIdx.x < 64) {
            const int ul = threadIdx.x;
            uh[b * 512 + u] = red[ul] + red[ul + 64] + red[ul + 128] + red[ul + 192]
                            + Ub[u] + Wb[u];
        }
    } else {
        // fragment pack: 2 groups of 512 shorts per block
        __shared__ float t[32][17];
        const int tid = threadIdx.x;
        #pragma unroll
        for (int e = 0; e < 2; ++e) {
            const int g  = (pb - 256) * 2 + e;
            const int ks = g >> 5;
            const int n4 = g & 31;
            #pragma unroll
            for (int q = 0; q < 2; ++q) {
                const int idx = q * 256 + tid;          // 0..511
                const int dl  = idx >> 4;               // 0..31
                const int ul  = idx & 15;               // 0..15
                t[dl][ul] = Wk[(size_t)(ks * 32 + dl) * 512 + n4 * 16 + ul];
            }
            __syncthreads();
            #pragma unroll
            for (int q = 0; q < 2; ++q) {
                const int idx  = q * 256 + tid;         // 0..511
                const int j    = idx & 7;
                const int lc   = (idx >> 3) & 15;
                const int quad = idx >> 7;
                WkTf[(size_t)g * 512 + idx] = f2bf(t[quad * 8 + j][lc]);
            }
            __syncthreads();
        }
    }
}

// ------------------------------------------------ fused GEMM+tanh+Vk-dot
// grid 2048 m-tiles of 32 rows; 512 threads = 8 waves, wave wn owns cols
// wn*64..+63 (2 m-frags x 4 n-frags). A direct-from-global + in-reg cvt;
// B from fragment-packed WkTf (L2). NO LDS / NO barriers in k-loop.
__global__ __launch_bounds__(512, 4) void attn_gemm(
    const float* __restrict__ feats, const ushort_t* __restrict__ WkTf,
    const float* __restrict__ uh, const float* __restrict__ Vk,
    float* __restrict__ lg)
{
    __shared__ float uh_s[512];
    __shared__ float vk_s[512];
    __shared__ float lpart[8][32];

    const int tid  = threadIdx.x;
    const int lane = tid & 63;
    const int quad = lane >> 4;
    const int lc   = lane & 15;
    const int wn   = tid >> 6;       // 0..7  (64-col strip)
    const int m0   = blockIdx.x * 32;
    const int bidx = m0 >> 11;       // batch index (uniform per block)

    // wave wn writes exactly uh_s[wn*64 .. +63] and reads only that slice
    // in its own epilogue -> no barrier needed for uh_s/vk_s.
    uh_s[tid] = uh[bidx * 512 + tid];
    vk_s[tid] = Vk[tid];

    // A bases: lane(quad,lc) of m-frag mf reads feats[m0+mf*16+lc][k0+quad*8..+7]
    const float* a_base0 = feats + (size_t)(m0 + lc) * 512 + quad * 8;
    const float* a_base1 = feats + (size_t)(m0 + 16 + lc) * 512 + quad * 8;
    // B base: groups g = ks*32 + (wn*4 + nf)
    const ushort_t* b_base = WkTf + (size_t)(wn * 4) * 512 + quad * 128 + lc * 8;

    f32x4 acc[2][4];
    #pragma unroll
    for (int tm = 0; tm < 2; ++tm)
        #pragma unroll
        for (int tn = 0; tn < 4; ++tn)
            acc[tm][tn] = (f32x4){0.f, 0.f, 0.f, 0.f};

    f32x4 a[2][2][2];    // [buf][mfrag][half]
    short8 b[2][4];      // [buf][nfrag]

    // prologue: ks=0 into buf 0
    a[0][0][0] = *(const f32x4*)(a_base0);
    a[0][0][1] = *(const f32x4*)(a_base0 + 4);
    a[0][1][0] = *(const f32x4*)(a_base1);
    a[0][1][1] = *(const f32x4*)(a_base1 + 4);
    #pragma unroll
    for (int nf = 0; nf < 4; ++nf)
        b[0][nf] = *(const short8*)(b_base + nf * 512);

    #pragma unroll
    for (int ks = 0; ks < 16; ++ks) {   // K = 512, BK = 32; fully unrolled,
        const int cur = ks & 1;         // all reg indices compile-time.
        const int nxt = cur ^ 1;
        if (ks < 15) {
            const int ko = (ks + 1) * 32;       // imm-offset range (<=2KB)
            a[nxt][0][0] = *(const f32x4*)(a_base0 + ko);
            a[nxt][0][1] = *(const f32x4*)(a_base0 + ko + 4);
            a[nxt][1][0] = *(const f32x4*)(a_base1 + ko);
            a[nxt][1][1] = *(const f32x4*)(a_base1 + ko + 4);
            const ushort_t* bk = b_base + (size_t)(ks + 1) * 16384;
            #pragma unroll
            for (int nf = 0; nf < 4; ++nf)
                b[nxt][nf] = *(const short8*)(bk + nf * 512);
        }
        short8 af0 = cvt8(a[cur][0][0], a[cur][0][1]);
        short8 af1 = cvt8(a[cur][1][0], a[cur][1][1]);
        #pragma unroll
        for (int tn = 0; tn < 4; ++tn) {
            acc[0][tn] = __builtin_amdgcn_mfma_f32_16x16x32_bf16(
                af0, b[cur][tn], acc[0][tn], 0, 0, 0);
            acc[1][tn] = __builtin_amdgcn_mfma_f32_16x16x32_bf16(
                af1, b[cur][tn], acc[1][tn], 0, 0, 0);
        }
    }

    // epilogue: tanh(acc + uh) * Vk -> per-row partials over this 64-N strip
    // C/D layout: col = lane&15, row = quad*4 + reg   [m89-verified]
    float rp[8];
    #pragma unroll
    for (int i = 0; i < 8; ++i) rp[i] = 0.f;
    #pragma unroll
    for (int tn = 0; tn < 4; ++tn) {
        const int nl  = wn * 64 + tn * 16 + lc;
        const float uhv = uh_s[nl];
        const float vkv = vk_s[nl];
        #pragma unroll
        for (int tm = 0; tm < 2; ++tm)
            #pragma unroll
            for (int i = 0; i < 4; ++i) {
                const float x = acc[tm][tn][i] + uhv;
                const float e = __expf(2.0f * x);          // tanh = 1 - 2/(e^{2x}+1)
                rp[tm * 4 + i] += (1.0f - 2.0f / (e + 1.0f)) * vkv;
            }
    }
    #pragma unroll
    for (int i = 0; i < 8; ++i) {
        float v = rp[i];
        v += __shfl_xor(v, 1, 64);
        v += __shfl_xor(v, 2, 64);
        v += __shfl_xor(v, 4, 64);
        v += __shfl_xor(v, 8, 64);
        rp[i] = v;
    }
    if (lc == 0) {
        #pragma unroll
        for (int tm = 0; tm < 2; ++tm)
            #pragma unroll
            for (int i = 0; i < 4; ++i)
                lpart[wn][tm * 16 + quad * 4 + i] = rp[tm * 4 + i];
    }
    __syncthreads();
    if (tid < 32) {
        float s = 0.f;
        #pragma unroll
        for (int j = 0; j < 8; ++j) s += lpart[j][tid];
        lg[m0 + tid] = s;
    }
}

// ---------------------------------------------------------------- softmax
__global__ __launch_bounds__(256) void softmax_k(
    const float* __restrict__ lg, float* __restrict__ aw_out)
{
    const int b = blockIdx.x, tid = threadIdx.x;
    const float* p = lg + b * 2048;
    float v[8];
    #pragma unroll
    for (int i = 0; i < 8; ++i) v[i] = p[tid + i * 256];
    float mx = -1e30f;
    #pragma unroll
    for (int i = 0; i < 8; ++i) mx = fmaxf(mx, v[i]);
    #pragma unroll
    for (int off = 32; off >= 1; off >>= 1) mx = fmaxf(mx, __shfl_xor(mx, off, 64));
    __shared__ float redm[4], reds[4];
    const int wv = tid >> 6, ln = tid & 63;
    if (ln == 0) redm[wv] = mx;
    __syncthreads();
    mx = fmaxf(fmaxf(redm[0], redm[1]), fmaxf(redm[2], redm[3]));
    float s = 0.f;
    #pragma unroll
    for (int i = 0; i < 8; ++i) { v[i] = __expf(v[i] - mx); s += v[i]; }
    #pragma unroll
    for (int off = 32; off >= 1; off >>= 1) s += __shfl_xor(s, off, 64);
    if (ln == 0) reds[wv] = s;
    __syncthreads();
    s = reds[0] + reds[1] + reds[2] + reds[3];
    const float inv = 1.0f / s;
    #pragma unroll
    for (int i = 0; i < 8; ++i)
        aw_out[b * 2048 + tid + i * 256] = v[i] * inv;
}

// ------------------------------------------------------- context, stage 1
// grid 512 = 32 b x 16 t-chunks(128); two 64-t halves per block write
// DISJOINT partial slots (no atomics). part[b][chunk*2+half][d].
__global__ __launch_bounds__(256) void context_part(
    const float* __restrict__ feats, const float* __restrict__ aw,
    float* __restrict__ part)
{
    const int b     = blockIdx.x >> 4;
    const int chunk = blockIdx.x & 15;
    const int half  = threadIdx.x >> 7;
    const int t0    = chunk * 128 + half * 64;
    const int d4    = (threadIdx.x & 127) * 4;
    const float* wp = aw + b * 2048 + t0;
    const float* fp = feats + (size_t)(b * 2048 + t0) * 512 + d4;
    f32x4 a = (f32x4){0.f, 0.f, 0.f, 0.f};
    #pragma unroll 4
    for (int tt = 0; tt < 64; ++tt) {
        const float w = wp[tt];
        const f32x4 f = *(const f32x4*)(fp + (size_t)tt * 512);
        a.x += w * f.x; a.y += w * f.y; a.z += w * f.z; a.w += w * f.w;
    }
    *(f32x4*)(part + (size_t)(b * 32 + chunk * 2 + half) * 512 + d4) = a;
}

// ------------------------------------------------------- context, stage 2
// grid 32 (b) x 512 threads (d): ctx[b][d] = sum_j part[b][j][d], j<32.
__global__ __launch_bounds__(512) void context_reduce(
    const float* __restrict__ part, float* __restrict__ ctx)
{
    const int b = blockIdx.x;
    const int d = threadIdx.x;
    const float* p = part + (size_t)b * 32 * 512 + d;
    float s = 0.f;
    #pragma unroll
    for (int j = 0; j < 32; ++j) s += p[j * 512];
    ctx[b * 512 + d] = s;
}

// ---------------------------------------------------------------- launch
extern "C" void kernel_launch(void* const* d_in, const int* in_sizes, int n_in,
                              void* d_out, int out_size, void* d_ws, size_t ws_size,
                              hipStream_t stream)
{
    const float* feats  = (const float*)d_in[0];
    const float* hidden = (const float*)d_in[1];
    const float* Wk     = (const float*)d_in[2];
    const float* Wb     = (const float*)d_in[3];
    const float* Uk     = (const float*)d_in[4];
    const float* Ub     = (const float*)d_in[5];
    const float* Vk     = (const float*)d_in[6];
    // d_in[7] = Vb: constant logit shift, cancels in softmax.

    float* out       = (float*)d_out;
    float* ctx_out_p = out;               // [32*512]  fp32
    float* aw_out_p  = out + 16384;       // [32*2048] fp32

    char* ws = (char*)d_ws;
    float*    uh   = (float*)ws;                      // 64 KB
    ushort_t* WkTf = (ushort_t*)(ws + 65536);         // 512 KB (fragment-ordered)
    float*    lg   = (float*)(ws + 589824);           // 256 KB
    float*    part = (float*)(ws + 851968);           // 2 MB  (32*32*512 f32)

    prep_all      <<<512, 256, 0, stream>>>(hidden, Uk, Ub, Wb, Wk, uh, WkTf);
    attn_gemm     <<<2048, 512, 0, stream>>>(feats, WkTf, uh, Vk, lg);
    softmax_k     <<<32,  256, 0, stream>>>(lg, aw_out_p);
    context_part  <<<512, 256, 0, stream>>>(feats, aw_out_p, part);
    context_reduce<<<32,  512, 0, stream>>>(part, ctx_out_p);
}

// Round 6
// 263.807 us; speedup vs baseline: 1.4232x; 1.4232x over previous
//
#include <hip/hip_runtime.h>
#include <stdint.h>

// Bahdanau additive attention, MI355X / gfx950.
// Inputs fp32, outputs fp32 (ctx[32*512] ++ aw[32*2048]).
// B=32, T=2048, D=512, U=512.  M = B*T = 65536.
//
// R14: attn_gemm REVERTED to verified R2 (77us; three structural rewrites
//      R11/R12/R13 = 95/105/201us all lost — R13's VGPR=36 shows the compiler
//      wouldn't hold the reg double-buffer). New target: the stable ~100us
//      residual of small kernels (total - fill(77) - gemm). Changes:
//      (a) softmax fused into context pass (redundant per-block softmax from
//          lg, chunk 0 writes aw) -> 5 dispatches -> 4;
//      (b) context parallelism 512 -> 2048 blocks (8/CU) to fix the
//          latency-starved 64-serial-load loop (2 blocks/CU before);
//      (c) partials + small reduce (no atomics, R10-verified).
// R13: no-barrier reg-pipeline: failed (VGPR cap). R12: 128x128+occupancy:
//      failed. R11: B-from-L2: failed. R10: atomics removed. R8: swizzles.

typedef unsigned short ushort_t;
typedef __attribute__((ext_vector_type(8))) short short8;
typedef __attribute__((ext_vector_type(4))) float f32x4;
typedef __attribute__((ext_vector_type(2))) float float2v;
typedef __attribute__((ext_vector_type(2))) __bf16 bf162v;

#define GLOBAL_AS __attribute__((address_space(1)))
#define LDS_AS    __attribute__((address_space(3)))

__device__ __forceinline__ ushort_t f2bf(float f) {
    uint32_t u = __builtin_bit_cast(uint32_t, f);
    u = (u + 0x7fffu + ((u >> 16) & 1u)) >> 16;   // RNE
    return (ushort_t)u;
}
__device__ __forceinline__ uint32_t pkbf(float a, float b) {
    bf162v r = __builtin_convertvector((float2v){a, b}, bf162v);
    return __builtin_bit_cast(uint32_t, r);
}

// --------------------------- fused prep: uh GEMV + WkT transpose (R2 verbatim)
// grid 512 = 256 uh | 256 WkT.  WkT[u][d] = bf16(Wk[d][u]).
__global__ __launch_bounds__(256) void prep_all(
    const float* __restrict__ hidden, const float* __restrict__ Uk,
    const float* __restrict__ Ub, const float* __restrict__ Wb,
    const float* __restrict__ Wk,
    float* __restrict__ uh, ushort_t* __restrict__ WkT)
{
    const int pb = blockIdx.x;
    if (pb < 256) {
        const int b  = pb >> 3;
        const int u  = (pb & 7) * 64 + (threadIdx.x & 63);
        const int k0 = (threadIdx.x >> 6) * 128;
        const float* hr = hidden + b * 512;
        float acc = 0.f;
        #pragma unroll 8
        for (int k = k0; k < k0 + 128; ++k)
            acc += hr[k] * Uk[k * 512 + u];
        __shared__ float red[256];
        red[threadIdx.x] = acc;
        __syncthreads();
        if (threadIdx.x < 64) {
            const int ul = threadIdx.x;
            uh[b * 512 + u] = red[ul] + red[ul + 64] + red[ul + 128] + red[ul + 192]
                            + Ub[u] + Wb[u];
        }
    } else {
        __shared__ float t[32][33];
        const int blk = pb - 256;
        const int ti = blk >> 4;
        const int tj = blk & 15;
        const int tx = threadIdx.x & 31;
        const int ty = threadIdx.x >> 5;
        #pragma unroll
        for (int q = 0; q < 4; ++q) {
            const int r = ty * 4 + q;
            t[r][tx] = Wk[(ti * 32 + r) * 512 + tj * 32 + tx];
        }
        __syncthreads();
        #pragma unroll
        for (int q = 0; q < 4; ++q) {
            const int r = ty * 4 + q;
            WkT[(tj * 32 + r) * 512 + ti * 32 + tx] = f2bf(t[tx][r]);
        }
    }
}

// ------------------------------------------------ fused GEMM+tanh+Vk-dot
// R2-VERIFIED VERSION (77us, MfmaUtil 17.9%) — byte-identical.
// grid 512 M-tiles of 128 rows; 1024 threads = 16 waves (2M x 8N, 64x64 each).
#define APAD 40   // A row stride in shorts (2-way banks = free)
__global__ __launch_bounds__(1024, 4) void attn_gemm(
    const float* __restrict__ feats, const ushort_t* __restrict__ WkT,
    const float* __restrict__ uh, const float* __restrict__ Vk,
    float* __restrict__ lg)
{
    __shared__ __align__(16) short As[2][128 * APAD];
    __shared__ __align__(16) short Bs[2][512 * 32];
    __shared__ float uh_s[512];
    __shared__ float vk_s[512];
    __shared__ float lpart[8][128];

    const int tid  = threadIdx.x;
    const int lane = tid & 63;
    const int quad = lane >> 4;
    const int lc   = lane & 15;
    const int wave = tid >> 6;       // 0..15
    const int wm   = wave >> 3;      // 0..1  (64-row strip)
    const int wn   = wave & 7;       // 0..7  (64-col strip)
    const int m0   = blockIdx.x * 128;
    const int bidx = m0 >> 11;       // batch index (uniform per block)

    if (tid < 512) {
        uh_s[tid] = uh[bidx * 512 + tid];
        vk_s[tid] = Vk[tid];
    }

    const int rowA = tid >> 3;          // 0..127
    const int kAo  = (tid & 7) * 4;     // fp32 k-offset 0..28
    // B staging swizzle: lds slot s of row r holds global k-slot s ^ ((r>>1)&3)
    const int rB0  = tid >> 2;          // rnd 0 row (0..255)
    const int sB   = tid & 3;           // lds k-slot

    f32x4 acc[4][4];
    #pragma unroll
    for (int tm = 0; tm < 4; ++tm)
        #pragma unroll
        for (int tn = 0; tn < 4; ++tn)
            acc[tm][tn] = (f32x4){0.f, 0.f, 0.f, 0.f};

    // ---- prologue: stage chunk 0 into buf 0
    {
        #pragma unroll
        for (int rnd = 0; rnd < 2; ++rnd) {
            const int li = rnd * 1024 + tid;
            const int rB = rnd * 256 + rB0;
            const int kq = (sB ^ ((rB >> 1) & 3)) * 8;
            const ushort_t* gb = WkT + (size_t)rB * 512 + kq;
            __builtin_amdgcn_global_load_lds(
                (const GLOBAL_AS void*)gb, (LDS_AS void*)(Bs[0] + li * 8), 16, 0, 0);
        }
        const f32x4 av = *(const f32x4*)(feats + (size_t)(m0 + rowA) * 512 + kAo);
        uint2 w;
        w.x = pkbf(av.x, av.y);
        w.y = pkbf(av.z, av.w);
        *(uint2*)(As[0] + rowA * APAD + kAo) = w;
    }

    const int swzR = (lc >> 1) & 3;     // fragment-read swizzle (row = ...+lc)

    int buf = 0;
    for (int ks = 0; ks < 16; ++ks) {   // K = 512, BK = 32
        __syncthreads();                // staging of `buf` complete

        f32x4 a_next;
        const bool have = (ks + 1) < 16;
        if (have) {
            const int k0n = (ks + 1) * 32;
            #pragma unroll
            for (int rnd = 0; rnd < 2; ++rnd) {
                const int li = rnd * 1024 + tid;
                const int rB = rnd * 256 + rB0;
                const int kq = (sB ^ ((rB >> 1) & 3)) * 8;
                const ushort_t* gb = WkT + (size_t)rB * 512 + k0n + kq;
                __builtin_amdgcn_global_load_lds(
                    (const GLOBAL_AS void*)gb, (LDS_AS void*)(Bs[buf ^ 1] + li * 8),
                    16, 0, 0);
            }
            a_next = *(const f32x4*)(feats + (size_t)(m0 + rowA) * 512 + k0n + kAo);
        }

        // ---- compute on `buf` (hides the loads above)
        short8 af[4], bfr[4];
        #pragma unroll
        for (int t4 = 0; t4 < 4; ++t4) {
            af[t4]  = *(const short8*)(As[buf] + (wm * 64 + t4 * 16 + lc) * APAD + quad * 8);
            bfr[t4] = *(const short8*)(Bs[buf] + (wn * 64 + t4 * 16 + lc) * 32
                                       + ((quad ^ swzR) * 8));
        }
        #pragma unroll
        for (int tm = 0; tm < 4; ++tm)
            #pragma unroll
            for (int tn = 0; tn < 4; ++tn)
                acc[tm][tn] = __builtin_amdgcn_mfma_f32_16x16x32_bf16(
                    af[tm], bfr[tn], acc[tm][tn], 0, 0, 0);

        if (have) {
            uint2 w;
            w.x = pkbf(a_next.x, a_next.y);
            w.y = pkbf(a_next.z, a_next.w);
            *(uint2*)(As[buf ^ 1] + rowA * APAD + kAo) = w;
        }
        buf ^= 1;
    }

    // epilogue: tanh(acc + uh) * Vk -> per-row partials
    // C/D layout: col = lane&15, row = quad*4 + reg   [m89-verified]
    float rp[16];
    #pragma unroll
    for (int i = 0; i < 16; ++i) rp[i] = 0.f;
    #pragma unroll
    for (int tn = 0; tn < 4; ++tn) {
        const int nl  = wn * 64 + tn * 16 + lc;
        const float uhv = uh_s[nl];
        const float vkv = vk_s[nl];
        #pragma unroll
        for (int tm = 0; tm < 4; ++tm)
            #pragma unroll
            for (int i = 0; i < 4; ++i) {
                const float x = acc[tm][tn][i] + uhv;
                const float e = __expf(2.0f * x);          // tanh = 1 - 2/(e^{2x}+1)
                rp[tm * 4 + i] += (1.0f - 2.0f / (e + 1.0f)) * vkv;
            }
    }
    #pragma unroll
    for (int i = 0; i < 16; ++i) {
        float v = rp[i];
        v += __shfl_xor(v, 1, 64);
        v += __shfl_xor(v, 2, 64);
        v += __shfl_xor(v, 4, 64);
        v += __shfl_xor(v, 8, 64);
        rp[i] = v;
    }
    if (lc == 0) {
        #pragma unroll
        for (int tm = 0; tm < 4; ++tm)
            #pragma unroll
            for (int i = 0; i < 4; ++i)
                lpart[wn][wm * 64 + tm * 16 + quad * 4 + i] = rp[tm * 4 + i];
    }
    __syncthreads();
    if (tid < 128) {
        float s = 0.f;
        #pragma unroll
        for (int j = 0; j < 8; ++j) s += lpart[j][tid];
        lg[m0 + tid] = s;
    }
}

// --------------------------------------- fused softmax + context partials
// grid 2048 = 32 b x 64 chunks(32 t); 256 thr. Every block redundantly
// computes the softmax normalizers for its batch from lg (8KB, L2-hot),
// chunk 0 also writes aw_out. Then each block computes the weighted
// feats-sum for its 32-row chunk -> disjoint partials (no atomics).
// part[b][chunk*2+half][d], half = rows 16.
__global__ __launch_bounds__(256) void softmax_ctx(
    const float* __restrict__ lg, const float* __restrict__ feats,
    float* __restrict__ aw_out, float* __restrict__ part)
{
    const int b     = blockIdx.x >> 6;
    const int chunk = blockIdx.x & 63;
    const int tid   = threadIdx.x;
    const float* p  = lg + b * 2048;

    // ---- softmax normalizers (identical math to old softmax_k)
    float v[8];
    #pragma unroll
    for (int i = 0; i < 8; ++i) v[i] = p[tid + i * 256];
    float mx = -1e30f;
    #pragma unroll
    for (int i = 0; i < 8; ++i) mx = fmaxf(mx, v[i]);
    #pragma unroll
    for (int off = 32; off >= 1; off >>= 1) mx = fmaxf(mx, __shfl_xor(mx, off, 64));
    __shared__ float redm[4], reds[4];
    const int wv = tid >> 6, ln = tid & 63;
    if (ln == 0) redm[wv] = mx;
    __syncthreads();
    mx = fmaxf(fmaxf(redm[0], redm[1]), fmaxf(redm[2], redm[3]));
    float s = 0.f;
    #pragma unroll
    for (int i = 0; i < 8; ++i) { v[i] = __expf(v[i] - mx); s += v[i]; }
    #pragma unroll
    for (int off = 32; off >= 1; off >>= 1) s += __shfl_xor(s, off, 64);
    if (ln == 0) reds[wv] = s;
    __syncthreads();
    s = reds[0] + reds[1] + reds[2] + reds[3];
    const float inv = 1.0f / s;

    if (chunk == 0) {
        #pragma unroll
        for (int i = 0; i < 8; ++i)
            aw_out[b * 2048 + tid + i * 256] = v[i] * inv;
    }

    // ---- weighted feats sum over this chunk's 32 rows (16 per half)
    const int half = tid >> 7;
    const int t0   = chunk * 32 + half * 16;
    const int d4   = (tid & 127) * 4;
    const float* wp = lg + b * 2048 + t0;                      // re-read logits
    const float* fp = feats + (size_t)(b * 2048 + t0) * 512 + d4;
    f32x4 a = (f32x4){0.f, 0.f, 0.f, 0.f};
    #pragma unroll 4
    for (int tt = 0; tt < 16; ++tt) {
        const float w = __expf(wp[tt] - mx) * inv;             // same math as aw
        const f32x4 f = *(const f32x4*)(fp + (size_t)tt * 512);
        a.x += w * f.x; a.y += w * f.y; a.z += w * f.z; a.w += w * f.w;
    }
    *(f32x4*)(part + (size_t)((b * 64 + chunk) * 2 + half) * 512 + d4) = a;
}

// ------------------------------------------------------- context reduce
// grid 256 = 32 b x 8 d-slices(64); 64 thr: ctx[b][d] = sum_j part[b][j][d].
__global__ __launch_bounds__(64) void context_reduce(
    const float* __restrict__ part, float* __restrict__ ctx)
{
    const int b = blockIdx.x >> 3;
    const int d = (blockIdx.x & 7) * 64 + threadIdx.x;
    const float* p = part + (size_t)b * 128 * 512 + d;
    float s = 0.f;
    #pragma unroll 8
    for (int j = 0; j < 128; ++j) s += p[j * 512];
    ctx[b * 512 + d] = s;
}

// ---------------------------------------------------------------- launch
extern "C" void kernel_launch(void* const* d_in, const int* in_sizes, int n_in,
                              void* d_out, int out_size, void* d_ws, size_t ws_size,
                              hipStream_t stream)
{
    const float* feats  = (const float*)d_in[0];
    const float* hidden = (const float*)d_in[1];
    const float* Wk     = (const float*)d_in[2];
    const float* Wb     = (const float*)d_in[3];
    const float* Uk     = (const float*)d_in[4];
    const float* Ub     = (const float*)d_in[5];
    const float* Vk     = (const float*)d_in[6];
    // d_in[7] = Vb: constant logit shift, cancels in softmax.

    float* out       = (float*)d_out;
    float* ctx_out_p = out;               // [32*512]  fp32
    float* aw_out_p  = out + 16384;       // [32*2048] fp32

    char* ws = (char*)d_ws;
    float*    uh   = (float*)ws;                      // 64 KB
    ushort_t* WkT  = (ushort_t*)(ws + 65536);         // 512 KB
    float*    lg   = (float*)(ws + 589824);           // 256 KB
    float*    part = (float*)(ws + 851968);           // 8 MB (32*128*512 f32)

    prep_all      <<<512, 256, 0, stream>>>(hidden, Uk, Ub, Wb, Wk, uh, WkT);
    attn_gemm     <<<512, 1024, 0, stream>>>(feats, WkT, uh, Vk, lg);
    softmax_ctx   <<<2048, 256, 0, stream>>>(lg, feats, aw_out_p, part);
    context_reduce<<<256, 64, 0, stream>>>(part, ctx_out_p);
}

// Round 7
// 262.573 us; speedup vs baseline: 1.4299x; 1.0047x over previous
//
#include <hip/hip_runtime.h>
#include <stdint.h>

// Bahdanau additive attention, MI355X / gfx950.
// Inputs fp32, outputs fp32 (ctx[32*512] ++ aw[32*2048]).
// B=32, T=2048, D=512, U=512.  M = B*T = 65536.
//
// R15: T4 counted-vmcnt on the verified R2 attn_gemm skeleton. R2's limit is
//      the m233 2-phase stall: __syncthreads' implied vmcnt(0) drains the
//      just-issued B prefetch every k-step (1 block/CU, no overlap source).
//      Now: Bs TRIPLE-buffered, stage tile ks+2 each iter, barrier is
//      `s_waitcnt vmcnt(2) lgkmcnt(0); s_barrier` (vmcnt(0) only at ks=15)
//      -> tile ks+1/ks+2 loads stay in flight ACROSS the barrier (m218 lever).
//      a_next issued before B-stage so its compiler wait is vmcnt(2) not 0.
//      Tail kernels reverted to R2 exact (R14 fusion was +8us worse).
// R13/R12/R11: gemm rewrites all regressed (201/105/95 vs R2's 77) - reverted.
// R10: context atomics removed. R8: B swizzle (conflicts proven A-path-only).

typedef unsigned short ushort_t;
typedef __attribute__((ext_vector_type(8))) short short8;
typedef __attribute__((ext_vector_type(4))) float f32x4;
typedef __attribute__((ext_vector_type(2))) float float2v;
typedef __attribute__((ext_vector_type(2))) __bf16 bf162v;

#define GLOBAL_AS __attribute__((address_space(1)))
#define LDS_AS    __attribute__((address_space(3)))

__device__ __forceinline__ ushort_t f2bf(float f) {
    uint32_t u = __builtin_bit_cast(uint32_t, f);
    u = (u + 0x7fffu + ((u >> 16) & 1u)) >> 16;   // RNE
    return (ushort_t)u;
}
__device__ __forceinline__ uint32_t pkbf(float a, float b) {
    bf162v r = __builtin_convertvector((float2v){a, b}, bf162v);
    return __builtin_bit_cast(uint32_t, r);
}

// --------------------------- fused prep: uh GEMV + WkT transpose (R2 verbatim)
// grid 512 = 256 uh | 256 WkT.  WkT[u][d] = bf16(Wk[d][u]).
__global__ __launch_bounds__(256) void prep_all(
    const float* __restrict__ hidden, const float* __restrict__ Uk,
    const float* __restrict__ Ub, const float* __restrict__ Wb,
    const float* __restrict__ Wk,
    float* __restrict__ uh, ushort_t* __restrict__ WkT)
{
    const int pb = blockIdx.x;
    if (pb < 256) {
        const int b  = pb >> 3;
        const int u  = (pb & 7) * 64 + (threadIdx.x & 63);
        const int k0 = (threadIdx.x >> 6) * 128;
        const float* hr = hidden + b * 512;
        float acc = 0.f;
        #pragma unroll 8
        for (int k = k0; k < k0 + 128; ++k)
            acc += hr[k] * Uk[k * 512 + u];
        __shared__ float red[256];
        red[threadIdx.x] = acc;
        __syncthreads();
        if (threadIdx.x < 64) {
            const int ul = threadIdx.x;
            uh[b * 512 + u] = red[ul] + red[ul + 64] + red[ul + 128] + red[ul + 192]
                            + Ub[u] + Wb[u];
        }
    } else {
        __shared__ float t[32][33];
        const int blk = pb - 256;
        const int ti = blk >> 4;
        const int tj = blk & 15;
        const int tx = threadIdx.x & 31;
        const int ty = threadIdx.x >> 5;
        #pragma unroll
        for (int q = 0; q < 4; ++q) {
            const int r = ty * 4 + q;
            t[r][tx] = Wk[(ti * 32 + r) * 512 + tj * 32 + tx];
        }
        __syncthreads();
        #pragma unroll
        for (int q = 0; q < 4; ++q) {
            const int r = ty * 4 + q;
            WkT[(tj * 32 + r) * 512 + ti * 32 + tx] = f2bf(t[tx][r]);
        }
    }
}

// ------------------------------------------------ fused GEMM+tanh+Vk-dot
// R2 skeleton + counted-vmcnt barrier + triple-buffered B (prefetch depth 2).
// grid 512 M-tiles of 128 rows; 1024 threads = 16 waves (2M x 8N, 64x64 each).
#define APAD 40   // A row stride in shorts (2-way banks = free)
__global__ __launch_bounds__(1024, 4) void attn_gemm(
    const float* __restrict__ feats, const ushort_t* __restrict__ WkT,
    const float* __restrict__ uh, const float* __restrict__ Vk,
    float* __restrict__ lg)
{
    __shared__ __align__(16) short As[2][128 * APAD];     // 20.5 KB
    __shared__ __align__(16) short Bs_all[3][512 * 32];   // 96 KB
    __shared__ float uh_s[512];
    __shared__ float vk_s[512];
    __shared__ float lpart[8][128];

    const int tid  = threadIdx.x;
    const int lane = tid & 63;
    const int quad = lane >> 4;
    const int lc   = lane & 15;
    const int wave = tid >> 6;       // 0..15
    const int wm   = wave >> 3;      // 0..1  (64-row strip)
    const int wn   = wave & 7;       // 0..7  (64-col strip)
    const int m0   = blockIdx.x * 128;
    const int bidx = m0 >> 11;       // batch index (uniform per block)

    if (tid < 512) {
        uh_s[tid] = uh[bidx * 512 + tid];
        vk_s[tid] = Vk[tid];
    }

    const int rowA = tid >> 3;          // 0..127
    const int kAo  = (tid & 7) * 4;     // fp32 k-offset 0..28
    // B staging swizzle: lds slot s of row r holds global k-slot s ^ ((r>>1)&3)
    const int rB0  = tid >> 2;          // rnd 0 row (0..255)
    const int sB   = tid & 3;           // lds k-slot
    const int kqB  = (sB ^ ((rB0 >> 1) & 3)) * 8;   // same for both rnds (rB0+256: bit1 unchanged... recompute per rnd below)

    f32x4 acc[4][4];
    #pragma unroll
    for (int tm = 0; tm < 4; ++tm)
        #pragma unroll
        for (int tn = 0; tn < 4; ++tn)
            acc[tm][tn] = (f32x4){0.f, 0.f, 0.f, 0.f};

    // B triple-buffer rotation: Brd = tile ks, Bmid = ks+1, Bwr = stage ks+2
    short* Brd  = Bs_all[0];
    short* Bmid = Bs_all[1];
    short* Bwr  = Bs_all[2];

    // ---- prologue: A tile 0 (issue first -> its wait leaves B in flight),
    //      then stage B tiles 0 and 1.
    {
        const f32x4 av = *(const f32x4*)(feats + (size_t)(m0 + rowA) * 512 + kAo);
        #pragma unroll
        for (int pt = 0; pt < 2; ++pt) {            // B tiles 0,1
            short* dst = (pt == 0) ? Brd : Bmid;
            #pragma unroll
            for (int rnd = 0; rnd < 2; ++rnd) {
                const int li = rnd * 1024 + tid;
                const int rB = rnd * 256 + rB0;
                const int kq = (sB ^ ((rB >> 1) & 3)) * 8;
                const ushort_t* gb = WkT + (size_t)rB * 512 + pt * 32 + kq;
                __builtin_amdgcn_global_load_lds(
                    (const GLOBAL_AS void*)gb, (LDS_AS void*)(dst + li * 8), 16, 0, 0);
            }
        }
        uint2 w;
        w.x = pkbf(av.x, av.y);
        w.y = pkbf(av.z, av.w);
        *(uint2*)(As[0] + rowA * APAD + kAo) = w;
    }

    const int swzR = (lc >> 1) & 3;     // fragment-read swizzle (row = ...+lc)

    int buf = 0;
    for (int ks = 0; ks < 16; ++ks) {   // K = 512, BK = 32
        // counted-vmcnt barrier: tile ks resident when <=2 younger B loads
        // (tile ks+1's) remain in flight; lgkmcnt(0) covers As ds_writes.
        if (ks < 15) {
            asm volatile("s_waitcnt vmcnt(2) lgkmcnt(0)" ::: "memory");
        } else {
            asm volatile("s_waitcnt vmcnt(0) lgkmcnt(0)" ::: "memory");
        }
        __builtin_amdgcn_s_barrier();

        f32x4 a_next;
        const bool haveA = (ks + 1) < 16;
        if (haveA)                       // issued BEFORE B-stage: its use-wait
            a_next = *(const f32x4*)(feats + (size_t)(m0 + rowA) * 512
                                     + (ks + 1) * 32 + kAo);   // becomes vmcnt(2)

        if (ks + 2 < 16) {               // stage tile ks+2 into Bwr
            const int k0n = (ks + 2) * 32;
            #pragma unroll
            for (int rnd = 0; rnd < 2; ++rnd) {
                const int li = rnd * 1024 + tid;
                const int rB = rnd * 256 + rB0;
                const int kq = (sB ^ ((rB >> 1) & 3)) * 8;
                const ushort_t* gb = WkT + (size_t)rB * 512 + k0n + kq;
                __builtin_amdgcn_global_load_lds(
                    (const GLOBAL_AS void*)gb, (LDS_AS void*)(Bwr + li * 8), 16, 0, 0);
            }
        }

        // ---- compute on As[buf] / Brd
        short8 af[4], bfr[4];
        #pragma unroll
        for (int t4 = 0; t4 < 4; ++t4) {
            af[t4]  = *(const short8*)(As[buf] + (wm * 64 + t4 * 16 + lc) * APAD + quad * 8);
            bfr[t4] = *(const short8*)(Brd + (wn * 64 + t4 * 16 + lc) * 32
                                       + ((quad ^ swzR) * 8));
        }
        #pragma unroll
        for (int tm = 0; tm < 4; ++tm)
            #pragma unroll
            for (int tn = 0; tn < 4; ++tn)
                acc[tm][tn] = __builtin_amdgcn_mfma_f32_16x16x32_bf16(
                    af[tm], bfr[tn], acc[tm][tn], 0, 0, 0);

        if (haveA) {
            uint2 w;
            w.x = pkbf(a_next.x, a_next.y);
            w.y = pkbf(a_next.z, a_next.w);
            *(uint2*)(As[buf ^ 1] + rowA * APAD + kAo) = w;
        }
        buf ^= 1;

        // rotate B buffers: ks+1 becomes current, old current becomes stage
        short* t = Brd; Brd = Bmid; Bmid = Bwr; Bwr = t;
    }

    // epilogue: tanh(acc + uh) * Vk -> per-row partials
    // C/D layout: col = lane&15, row = quad*4 + reg   [m89-verified]
    float rp[16];
    #pragma unroll
    for (int i = 0; i < 16; ++i) rp[i] = 0.f;
    #pragma unroll
    for (int tn = 0; tn < 4; ++tn) {
        const int nl  = wn * 64 + tn * 16 + lc;
        const float uhv = uh_s[nl];
        const float vkv = vk_s[nl];
        #pragma unroll
        for (int tm = 0; tm < 4; ++tm)
            #pragma unroll
            for (int i = 0; i < 4; ++i) {
                const float x = acc[tm][tn][i] + uhv;
                const float e = __expf(2.0f * x);          // tanh = 1 - 2/(e^{2x}+1)
                rp[tm * 4 + i] += (1.0f - 2.0f / (e + 1.0f)) * vkv;
            }
    }
    #pragma unroll
    for (int i = 0; i < 16; ++i) {
        float v = rp[i];
        v += __shfl_xor(v, 1, 64);
        v += __shfl_xor(v, 2, 64);
        v += __shfl_xor(v, 4, 64);
        v += __shfl_xor(v, 8, 64);
        rp[i] = v;
    }
    if (lc == 0) {
        #pragma unroll
        for (int tm = 0; tm < 4; ++tm)
            #pragma unroll
            for (int i = 0; i < 4; ++i)
                lpart[wn][wm * 64 + tm * 16 + quad * 4 + i] = rp[tm * 4 + i];
    }
    __syncthreads();
    if (tid < 128) {
        float s = 0.f;
        #pragma unroll
        for (int j = 0; j < 8; ++j) s += lpart[j][tid];
        lg[m0 + tid] = s;
    }
}

// ---------------------------------------------------------------- softmax
__global__ __launch_bounds__(256) void softmax_k(
    const float* __restrict__ lg, float* __restrict__ aw_out)
{
    const int b = blockIdx.x, tid = threadIdx.x;
    const float* p = lg + b * 2048;
    float v[8];
    #pragma unroll
    for (int i = 0; i < 8; ++i) v[i] = p[tid + i * 256];
    float mx = -1e30f;
    #pragma unroll
    for (int i = 0; i < 8; ++i) mx = fmaxf(mx, v[i]);
    #pragma unroll
    for (int off = 32; off >= 1; off >>= 1) mx = fmaxf(mx, __shfl_xor(mx, off, 64));
    __shared__ float redm[4], reds[4];
    const int wv = tid >> 6, ln = tid & 63;
    if (ln == 0) redm[wv] = mx;
    __syncthreads();
    mx = fmaxf(fmaxf(redm[0], redm[1]), fmaxf(redm[2], redm[3]));
    float s = 0.f;
    #pragma unroll
    for (int i = 0; i < 8; ++i) { v[i] = __expf(v[i] - mx); s += v[i]; }
    #pragma unroll
    for (int off = 32; off >= 1; off >>= 1) s += __shfl_xor(s, off, 64);
    if (ln == 0) reds[wv] = s;
    __syncthreads();
    s = reds[0] + reds[1] + reds[2] + reds[3];
    const float inv = 1.0f / s;
    #pragma unroll
    for (int i = 0; i < 8; ++i)
        aw_out[b * 2048 + tid + i * 256] = v[i] * inv;
}

// ------------------------------------------------------- context, stage 1
// grid 512 = 32 b x 16 t-chunks(128); two 64-t halves per block write
// DISJOINT partial slots (no atomics). part[b][chunk*2+half][d].
__global__ __launch_bounds__(256) void context_part(
    const float* __restrict__ feats, const float* __restrict__ aw,
    float* __restrict__ part)
{
    const int b     = blockIdx.x >> 4;
    const int chunk = blockIdx.x & 15;
    const int half  = threadIdx.x >> 7;
    const int t0    = chunk * 128 + half * 64;
    const int d4    = (threadIdx.x & 127) * 4;
    const float* wp = aw + b * 2048 + t0;
    const float* fp = feats + (size_t)(b * 2048 + t0) * 512 + d4;
    f32x4 a = (f32x4){0.f, 0.f, 0.f, 0.f};
    #pragma unroll 4
    for (int tt = 0; tt < 64; ++tt) {
        const float w = wp[tt];
        const f32x4 f = *(const f32x4*)(fp + (size_t)tt * 512);
        a.x += w * f.x; a.y += w * f.y; a.z += w * f.z; a.w += w * f.w;
    }
    *(f32x4*)(part + (size_t)(b * 32 + chunk * 2 + half) * 512 + d4) = a;
}

// ------------------------------------------------------- context, stage 2
// grid 32 (b) x 512 threads (d): ctx[b][d] = sum_j part[b][j][d], j<32.
__global__ __launch_bounds__(512) void context_reduce(
    const float* __restrict__ part, float* __restrict__ ctx)
{
    const int b = blockIdx.x;
    const int d = threadIdx.x;
    const float* p = part + (size_t)b * 32 * 512 + d;
    float s = 0.f;
    #pragma unroll
    for (int j = 0; j < 32; ++j) s += p[j * 512];
    ctx[b * 512 + d] = s;
}

// ---------------------------------------------------------------- launch
extern "C" void kernel_launch(void* const* d_in, const int* in_sizes, int n_in,
                              void* d_out, int out_size, void* d_ws, size_t ws_size,
                              hipStream_t stream)
{
    const float* feats  = (const float*)d_in[0];
    const float* hidden = (const float*)d_in[1];
    const float* Wk     = (const float*)d_in[2];
    const float* Wb     = (const float*)d_in[3];
    const float* Uk     = (const float*)d_in[4];
    const float* Ub     = (const float*)d_in[5];
    const float* Vk     = (const float*)d_in[6];
    // d_in[7] = Vb: constant logit shift, cancels in softmax.

    float* out       = (float*)d_out;
    float* ctx_out_p = out;               // [32*512]  fp32
    float* aw_out_p  = out + 16384;       // [32*2048] fp32

    char* ws = (char*)d_ws;
    float*    uh   = (float*)ws;                      // 64 KB
    ushort_t* WkT  = (ushort_t*)(ws + 65536);         // 512 KB
    float*    lg   = (float*)(ws + 589824);           // 256 KB
    float*    part = (float*)(ws + 851968);           // 2 MB  (32*32*512 f32)

    prep_all      <<<512, 256, 0, stream>>>(hidden, Uk, Ub, Wb, Wk, uh, WkT);
    attn_gemm     <<<512, 1024, 0, stream>>>(feats, WkT, uh, Vk, lg);
    softmax_k     <<<32,  256, 0, stream>>>(lg, aw_out_p);
    context_part  <<<512, 256, 0, stream>>>(feats, aw_out_p, part);
    context_reduce<<<32,  512, 0, stream>>>(part, ctx_out_p);
}